// Round 3
// baseline (283.838 us; speedup 1.0000x reference)
//
#include <hip/hip_runtime.h>

#define NCOL 1116
#define NLEV 7
#define NT 64
#define ARENA 2048   // floats of LDS per row (8 KB)
#define NRPW 2       // rows per wave (independent ILP streams)

namespace {
constexpr float DEC_LO[8] = {-0.010597401784997278f,  0.032883011666982945f,
                              0.030841381835986965f, -0.18703481171888114f,
                             -0.02798376941698385f,   0.6308807679295904f,
                              0.7148465705525415f,    0.23037781330885523f};
constexpr float DEC_HI[8] = {-0.23037781330885523f,   0.7148465705525415f,
                             -0.6308807679295904f,   -0.02798376941698385f,
                              0.18703481171888114f,   0.030841381835986965f,
                             -0.032883011666982945f, -0.010597401784997278f};
constexpr float REC_LO[8] = { 0.23037781330885523f,   0.7148465705525415f,
                              0.6308807679295904f,   -0.02798376941698385f,
                             -0.18703481171888114f,   0.030841381835986965f,
                              0.032883011666982945f, -0.010597401784997278f};
constexpr float REC_HI[8] = {-0.010597401784997278f, -0.032883011666982945f,
                              0.030841381835986965f,  0.18703481171888114f,
                             -0.02798376941698385f,  -0.6308807679295904f,
                              0.7148465705525415f,   -0.23037781330885523f};
// approx lengths per level
constexpr int alen[8] = {1116, 561, 284, 145, 76, 41, 24, 15};
// detail segment offsets in dpool (all even => 8B-aligned)
constexpr int doff[7] = {0, 562, 846, 992, 1068, 1110, 1134};
}

static __device__ __forceinline__ float softf(float c, float t) {
    return copysignf(fmaxf(fabsf(c) - t, 0.0f), c);
}

static __device__ __forceinline__ void dec8(const float* v, float& lo, float& hi) {
    float l = DEC_LO[7] * v[0];
    float h = DEC_HI[7] * v[0];
    #pragma unroll
    for (int s = 6; s >= 0; --s) {
        l = fmaf(DEC_LO[s], v[7 - s], l);
        h = fmaf(DEC_HI[s], v[7 - s], h);
    }
    lo = l; hi = h;
}

static __device__ __forceinline__ float2 rec_pair(float ca0, float ca1, float ca2, float ca3,
                                                  float cd0, float cd1, float cd2, float cd3) {
    float y0 = fmaf(REC_LO[0], ca3, fmaf(REC_LO[2], ca2, fmaf(REC_LO[4], ca1, REC_LO[6] * ca0)));
    y0 = fmaf(REC_HI[0], cd3, fmaf(REC_HI[2], cd2, fmaf(REC_HI[4], cd1, fmaf(REC_HI[6], cd0, y0))));
    float y1 = fmaf(REC_LO[1], ca3, fmaf(REC_LO[3], ca2, fmaf(REC_LO[5], ca1, REC_LO[7] * ca0)));
    y1 = fmaf(REC_HI[1], cd3, fmaf(REC_HI[3], cd2, fmaf(REC_HI[5], cd1, fmaf(REC_HI[7], cd0, y1))));
    return make_float2(y0, y1);
}

__global__ __launch_bounds__(NT)
void wavelet_kernel(const float* __restrict__ x,
                    const float* __restrict__ thr_ptr,
                    float* __restrict__ out, int nrow) {
    __shared__ __align__(16) float SH[NRPW * ARENA];

    const int lane = threadIdx.x;
    const int row0 = blockIdx.x * NRPW;
    if (row0 >= nrow) return;                 // 1 wave/block, no block barriers
    const int rows[2] = {row0, min(row0 + 1, nrow - 1)};

    const float thr = fmaxf(thr_ptr[0], 0.01f);

    float* dpool[NRPW]; float* b8[NRPW]; float* c8[NRPW];
    #pragma unroll
    for (int r = 0; r < NRPW; ++r) {
        float* a = SH + r * ARENA;
        dpool[r] = a;            // d0..d6 in [0,1150)
        b8[r]    = a + 1156;     // B data; region [1150,1726), 6 front pads
        c8[r]    = a + 1732;     // C data; region [1726,2048), 6 front pads
    }

    // ---- forward level 0: windows straight from global x ----
    {
        const float* xr[NRPW] = {x + (size_t)rows[0] * NCOL, x + (size_t)rows[1] * NCOL};
        #pragma unroll
        for (int k = 0; k < 9; ++k) {
            const int o = lane + (k << 6);
            if (k < 8 || lane < 49) {         // guard folds away for k<8
                #pragma unroll
                for (int r = 0; r < NRPW; ++r) {
                    float v[8];
                    bool fast = (k >= 1 && k <= 7);
                    if (!fast) fast = (o >= 3 && o <= 557);
                    if (fast) {
                        const float2* p = (const float2*)(xr[r] + 2 * o - 6);
                        float2 q0 = p[0], q1 = p[1], q2 = p[2], q3 = p[3];
                        v[0] = q0.x; v[1] = q0.y; v[2] = q1.x; v[3] = q1.y;
                        v[4] = q2.x; v[5] = q2.y; v[6] = q3.x; v[7] = q3.y;
                    } else {
                        #pragma unroll
                        for (int j = 0; j < 8; ++j) {
                            const int idx = 2 * o - 6 + j;
                            v[j] = (idx >= 0 && idx < NCOL) ? xr[r][idx] : 0.0f;
                        }
                    }
                    float lo, hi;
                    dec8(v, lo, hi);
                    b8[r][o]    = lo;                 // a1
                    dpool[r][o] = softf(hi, thr);     // d0
                }
            }
        }
        #pragma unroll
        for (int r = 0; r < NRPW; ++r)
            if (lane < 14) { const int j = lane < 6 ? lane - 6 : 555 + lane; b8[r][j] = 0.0f; }
        __builtin_amdgcn_wave_barrier();
    }

    // ---- forward levels 1..6 ----
    #pragma unroll
    for (int l = 1; l < NLEV; ++l) {
        const int nout = alen[l + 1];
        const int K = (nout + 63) >> 6;
        const int tailn = nout - ((K - 1) << 6);
        #pragma unroll
        for (int k = 0; k < K; ++k) {
            const int o = lane + (k << 6);
            if (k < K - 1 || lane < tailn) {  // guard only on tail iteration
                #pragma unroll
                for (int r = 0; r < NRPW; ++r) {
                    float* const cur = (l & 1) ? b8[r] : c8[r];
                    float* const nxt = (l & 1) ? c8[r] : b8[r];
                    const float2* p = (const float2*)(cur + 2 * o - 6);
                    float2 q0 = p[0], q1 = p[1], q2 = p[2], q3 = p[3];
                    float v[8] = {q0.x, q0.y, q1.x, q1.y, q2.x, q2.y, q3.x, q3.y};
                    float lo, hi;
                    dec8(v, lo, hi);
                    nxt[o] = (l == NLEV - 1) ? softf(lo, thr) : lo;   // a7 threshold fused
                    (dpool[r] + doff[l])[o] = softf(hi, thr);
                }
            }
        }
        if (l < NLEV - 1) {
            #pragma unroll
            for (int r = 0; r < NRPW; ++r)
                if (lane < 14) {
                    const int j = lane < 6 ? lane - 6 : nout + lane - 6;
                    ((l & 1) ? c8[r] : b8[r])[j] = 0.0f;
                }
        }
        __builtin_amdgcn_wave_barrier();
    }

    // ---- inverse levels 6..1 ----
    #pragma unroll
    for (int l = NLEV - 1; l >= 1; --l) {
        const int M = alen[l + 1];
        const int npair = M - 3;
        const int Qf = npair >> 1;                    // full quads
        const int KI = (Qf + 63) >> 6;
        const int tailq = Qf - ((KI - 1) << 6);
        #pragma unroll
        for (int k = 0; k < KI; ++k) {
            const int q = lane + (k << 6);
            if (k < KI - 1 || lane < tailq) {
                const int m = q << 1;
                #pragma unroll
                for (int r = 0; r < NRPW; ++r) {
                    const float* const cur = (l & 1) ? c8[r] : b8[r];   // a7 in B (l=6)
                    float* const nxt       = (l & 1) ? b8[r] : c8[r];
                    const float* const dp  = dpool[r] + doff[l];
                    const float2* pa = (const float2*)(cur + m);
                    const float2* pd = (const float2*)(dp + m);
                    float2 a01 = pa[0], a23 = pa[1];
                    float2 d01 = pd[0], d23 = pd[1];
                    float ca4 = cur[m + 4], cd4 = dp[m + 4];
                    float2 y01 = rec_pair(a01.x, a01.y, a23.x, a23.y, d01.x, d01.y, d23.x, d23.y);
                    float2 y23 = rec_pair(a01.y, a23.x, a23.y, ca4, d01.y, d23.x, d23.y, cd4);
                    *(float4*)(nxt + 2 * m) = make_float4(y01.x, y01.y, y23.x, y23.y);
                }
            }
        }
        if ((npair & 1) && lane == 0) {               // odd tail: one extra pair
            const int m = npair - 1;
            #pragma unroll
            for (int r = 0; r < NRPW; ++r) {
                const float* const cur = (l & 1) ? c8[r] : b8[r];
                float* const nxt       = (l & 1) ? b8[r] : c8[r];
                const float* const dp  = dpool[r] + doff[l];
                float2 y01 = rec_pair(cur[m], cur[m + 1], cur[m + 2], cur[m + 3],
                                      dp[m],  dp[m + 1],  dp[m + 2],  dp[m + 3]);
                *(float2*)(nxt + 2 * m) = y01;
            }
        }
        __builtin_amdgcn_wave_barrier();
    }

    // ---- inverse level 0: read B + d0, write global float4 ----
    {
        float4* orow[NRPW] = {(float4*)(out + (size_t)rows[0] * NCOL),
                              (float4*)(out + (size_t)rows[1] * NCOL)};
        #pragma unroll
        for (int k = 0; k < 5; ++k) {                 // Qf=279: 4 full + tail 23
            const int q = lane + (k << 6);
            if (k < 4 || lane < 23) {
                const int m = q << 1;
                #pragma unroll
                for (int r = 0; r < NRPW; ++r) {
                    const float* const cur = b8[r];   // a1' (562)
                    const float* const dp  = dpool[r];
                    const float2* pa = (const float2*)(cur + m);
                    const float2* pd = (const float2*)(dp + m);
                    float2 a01 = pa[0], a23 = pa[1];
                    float2 d01 = pd[0], d23 = pd[1];
                    float ca4 = cur[m + 4], cd4 = dp[m + 4];
                    float2 y01 = rec_pair(a01.x, a01.y, a23.x, a23.y, d01.x, d01.y, d23.x, d23.y);
                    float2 y23 = rec_pair(a01.y, a23.x, a23.y, ca4, d01.y, d23.x, d23.y, cd4);
                    orow[r][q] = make_float4(y01.x, y01.y, y23.x, y23.y);
                }
            }
        }
    }
}

extern "C" void kernel_launch(void* const* d_in, const int* in_sizes, int n_in,
                              void* d_out, int out_size, void* d_ws, size_t ws_size,
                              hipStream_t stream) {
    const float* x = (const float*)d_in[0];
    const float* thr = (const float*)d_in[1];
    float* out = (float*)d_out;
    const int nrow = in_sizes[0] / NCOL;
    const int nblk = (nrow + NRPW - 1) / NRPW;
    hipLaunchKernelGGL(wavelet_kernel, dim3(nblk), dim3(NT), 0, stream, x, thr, out, nrow);
}